// Round 6
// baseline (55.841 us; speedup 1.0000x reference)
//
#include <hip/hip_runtime.h>
#include <hip/hip_bf16.h>

// int8 row-quantized gather-dot, round 5 (fixed compile): non-temporal hints
// on streaming traffic (quantize f32 input; gather's index reads and output
// writes) so the per-XCD L2s keep the 12.8 MB int8 table instead of 12 MB of
// single-use stream data.

typedef float f32x4 __attribute__((ext_vector_type(4)));  // clang vector: OK for nontemporal builtins

#if __has_builtin(__builtin_amdgcn_sdot4)
__device__ inline int dot4i8(int a, int b, int c) {
    return __builtin_amdgcn_sdot4(a, b, c, false);
}
#else
__device__ inline int dot4i8(int a, int b, int c) {
#pragma unroll
    for (int k = 0; k < 4; ++k) {
        int ax = (int)(signed char)((a >> (8 * k)) & 0xFF);
        int bx = (int)(signed char)((b >> (8 * k)) & 0xFF);
        c += ax * bx;
    }
    return c;
}
#endif

__device__ inline unsigned pack4(float x0, float x1, float x2, float x3, float inv) {
    int b0 = __float2int_rn(x0 * inv) & 0xFF;
    int b1 = __float2int_rn(x1 * inv) & 0xFF;
    int b2 = __float2int_rn(x2 * inv) & 0xFF;
    int b3 = __float2int_rn(x3 * inv) & 0xFF;
    return (unsigned)(b0 | (b1 << 8) | (b2 << 16) | (b3 << 24));
}

// ---- Pass 1: f32 rows -> int8 rows + per-row scale ----
__global__ void quantize_rows_i8(const float* __restrict__ in,
                                 uint2* __restrict__ q,       // [rows*16]
                                 float* __restrict__ scales,  // [rows]
                                 int n_rows) {
    int tid  = blockIdx.x * blockDim.x + threadIdx.x;
    int lane = tid & 15;
    int row  = tid >> 4;
    if (row >= n_rows) return;

    const f32x4* p = reinterpret_cast<const f32x4*>(in + (size_t)row * 128);
    // single-use stream: non-temporal so it doesn't evict the int8 table
    f32x4 a = __builtin_nontemporal_load(p + lane);
    f32x4 b = __builtin_nontemporal_load(p + lane + 16);

    float m = fmaxf(fmaxf(fabsf(a.x), fabsf(a.y)), fmaxf(fabsf(a.z), fabsf(a.w)));
    m = fmaxf(m, fmaxf(fmaxf(fabsf(b.x), fabsf(b.y)), fmaxf(fabsf(b.z), fabsf(b.w))));
    m = fmaxf(m, __shfl_xor(m, 1));
    m = fmaxf(m, __shfl_xor(m, 2));
    m = fmaxf(m, __shfl_xor(m, 4));
    m = fmaxf(m, __shfl_xor(m, 8));

    float inv = (m > 0.f) ? 127.0f / m : 0.f;
    float s   = (m > 0.f) ? m * (1.0f / 127.0f) : 0.f;

    uint2 r;
    r.x = pack4(a.x, a.y, a.z, a.w, inv);
    r.y = pack4(b.x, b.y, b.z, b.w, inv);
    q[(size_t)row * 16 + lane] = r;   // keep cached: gather reads it next
    if (lane == 0) scales[row] = s;
}

// ---- Pass 2: per-edge int8 dot, 8 lanes/edge ----
__global__ void gather_dot_i8(const int4* __restrict__ q,      // rows of 8 int4
                              const float* __restrict__ scales,
                              const int* __restrict__ src,
                              const int* __restrict__ dst,
                              float* __restrict__ out, int n_edges) {
    int tid  = blockIdx.x * blockDim.x + threadIdx.x;
    int lane = tid & 7;
    int e    = tid >> 3;
    if (e >= n_edges) return;

    // single-use streams: non-temporal
    int s = __builtin_nontemporal_load(src + e);
    int d = __builtin_nontemporal_load(dst + e);

    int4 a = q[(size_t)s * 8 + lane];
    int4 b = q[(size_t)d * 8 + lane];
    float sc = scales[s] * scales[d];

    int acc = 0;
    acc = dot4i8(a.x, b.x, acc);
    acc = dot4i8(a.y, b.y, acc);
    acc = dot4i8(a.z, b.z, acc);
    acc = dot4i8(a.w, b.w, acc);

    acc += __shfl_xor(acc, 1);
    acc += __shfl_xor(acc, 2);
    acc += __shfl_xor(acc, 4);

    if (lane == 0) __builtin_nontemporal_store((float)acc * sc, out + e);
}

// ---- Fallback: direct f32 kernel (if d_ws too small) ----
__global__ void gather_dot_f32(const float* __restrict__ emb,
                               const int* __restrict__ src,
                               const int* __restrict__ dst,
                               float* __restrict__ out, int n_edges) {
    int tid  = blockIdx.x * blockDim.x + threadIdx.x;
    int lane = tid & 31;
    int edge = tid >> 5;
    if (edge >= n_edges) return;
    size_t s = (size_t)src[edge];
    size_t d = (size_t)dst[edge];
    float4 a = *(reinterpret_cast<const float4*>(emb + s * 128) + lane);
    float4 b = *(reinterpret_cast<const float4*>(emb + d * 128) + lane);
    float p = a.x * b.x + a.y * b.y + a.z * b.z + a.w * b.w;
    p += __shfl_xor(p, 1);
    p += __shfl_xor(p, 2);
    p += __shfl_xor(p, 4);
    p += __shfl_xor(p, 8);
    p += __shfl_xor(p, 16);
    if (lane == 0) out[edge] = p;
}

extern "C" void kernel_launch(void* const* d_in, const int* in_sizes, int n_in,
                              void* d_out, int out_size, void* d_ws, size_t ws_size,
                              hipStream_t stream) {
    const float* emb = (const float*)d_in[0];
    const int*   src = (const int*)d_in[1];
    const int*   dst = (const int*)d_in[2];
    float*       out = (float*)d_out;

    const int n_emb   = in_sizes[0];   // 12,800,000
    const int n_edges = in_sizes[1];   // 1,000,000
    const int n_rows  = n_emb / 128;   // 100,000

    const size_t q_bytes  = (size_t)n_rows * 128;
    const size_t sc_bytes = (size_t)n_rows * sizeof(float);

    if (ws_size >= q_bytes + sc_bytes) {
        uint2* qtab   = (uint2*)d_ws;
        float* scales = (float*)((char*)d_ws + q_bytes);

        {
            const int threads = 256;
            const int rows_per_block = threads / 16;
            const int blocks = (n_rows + rows_per_block - 1) / rows_per_block;
            quantize_rows_i8<<<blocks, threads, 0, stream>>>(emb, qtab, scales, n_rows);
        }
        {
            const int threads = 256;
            const int edges_per_block = threads / 8;
            const int blocks = (n_edges + edges_per_block - 1) / edges_per_block;
            gather_dot_i8<<<blocks, threads, 0, stream>>>(
                (const int4*)qtab, scales, src, dst, out, n_edges);
        }
    } else {
        const int threads = 256;
        const int edges_per_block = threads / 32;
        const int blocks = (n_edges + edges_per_block - 1) / edges_per_block;
        gather_dot_f32<<<blocks, threads, 0, stream>>>(emb, src, dst, out, n_edges);
    }
}

// Round 7
// 48.671 us; speedup vs baseline: 1.1473x; 1.1473x over previous
//
#include <hip/hip_runtime.h>
#include <hip/hip_bf16.h>

// int8 row-quantized gather-dot, round 7: NT hints reverted (round-6 showed
// they regress 8 us). Quantize restructured to 8 lanes/row (64 B/lane read,
// uint4 store) to close its gap to the streaming floor. Gather is round-4's
// (34 us, FETCH ~115 MB vs 102 MB structural floor at the ~3.4 TB/s L2-fill
// path), with the scale multiply moved to lane 0 only.

typedef float f32x4 __attribute__((ext_vector_type(4)));

#if __has_builtin(__builtin_amdgcn_sdot4)
__device__ inline int dot4i8(int a, int b, int c) {
    return __builtin_amdgcn_sdot4(a, b, c, false);
}
#else
__device__ inline int dot4i8(int a, int b, int c) {
#pragma unroll
    for (int k = 0; k < 4; ++k) {
        int ax = (int)(signed char)((a >> (8 * k)) & 0xFF);
        int bx = (int)(signed char)((b >> (8 * k)) & 0xFF);
        c += ax * bx;
    }
    return c;
}
#endif

__device__ inline unsigned pack4v(f32x4 v, float inv) {
    int b0 = __float2int_rn(v.x * inv) & 0xFF;
    int b1 = __float2int_rn(v.y * inv) & 0xFF;
    int b2 = __float2int_rn(v.z * inv) & 0xFF;
    int b3 = __float2int_rn(v.w * inv) & 0xFF;
    return (unsigned)(b0 | (b1 << 8) | (b2 << 16) | (b3 << 24));
}

__device__ inline float amax4(f32x4 v) {
    return fmaxf(fmaxf(fabsf(v.x), fabsf(v.y)), fmaxf(fabsf(v.z), fabsf(v.w)));
}

// ---- Pass 1: f32 rows -> int8 rows + per-row scale, 8 lanes/row ----
// Lane j loads f32x4 #j, #(j+8), #(j+16), #(j+24) (each load instr is 128 B
// contiguous across the 8-lane group), packs 16 int8 into one uint4 store.
// Packing order is lane-interleaved but identical for every row; the dot is
// permutation-invariant, so pass 2 stays element-matched.
__global__ void quantize_rows_i8(const float* __restrict__ in,
                                 uint4* __restrict__ q,       // [rows*8]
                                 float* __restrict__ scales,  // [rows]
                                 int n_rows) {
    int tid  = blockIdx.x * blockDim.x + threadIdx.x;
    int lane = tid & 7;
    int row  = tid >> 3;
    if (row >= n_rows) return;

    const f32x4* p = reinterpret_cast<const f32x4*>(in + (size_t)row * 128);
    f32x4 v0 = p[lane];
    f32x4 v1 = p[lane + 8];
    f32x4 v2 = p[lane + 16];
    f32x4 v3 = p[lane + 24];

    float m = fmaxf(fmaxf(amax4(v0), amax4(v1)), fmaxf(amax4(v2), amax4(v3)));
    m = fmaxf(m, __shfl_xor(m, 1));
    m = fmaxf(m, __shfl_xor(m, 2));
    m = fmaxf(m, __shfl_xor(m, 4));

    float inv = (m > 0.f) ? 127.0f / m : 0.f;
    float s   = (m > 0.f) ? m * (1.0f / 127.0f) : 0.f;

    uint4 r;
    r.x = pack4v(v0, inv);
    r.y = pack4v(v1, inv);
    r.z = pack4v(v2, inv);
    r.w = pack4v(v3, inv);
    q[(size_t)row * 8 + lane] = r;
    if (lane == 0) scales[row] = s;
}

// ---- Pass 2: per-edge int8 dot, 8 lanes/edge ----
__global__ void gather_dot_i8(const int4* __restrict__ q,      // rows of 8 int4
                              const float* __restrict__ scales,
                              const int* __restrict__ src,
                              const int* __restrict__ dst,
                              float* __restrict__ out, int n_edges) {
    int tid  = blockIdx.x * blockDim.x + threadIdx.x;
    int lane = tid & 7;
    int e    = tid >> 3;
    if (e >= n_edges) return;

    int s = src[e];
    int d = dst[e];

    int4 a = q[(size_t)s * 8 + lane];
    int4 b = q[(size_t)d * 8 + lane];

    int acc = 0;
    acc = dot4i8(a.x, b.x, acc);
    acc = dot4i8(a.y, b.y, acc);
    acc = dot4i8(a.z, b.z, acc);
    acc = dot4i8(a.w, b.w, acc);

    acc += __shfl_xor(acc, 1);
    acc += __shfl_xor(acc, 2);
    acc += __shfl_xor(acc, 4);

    if (lane == 0) out[e] = (float)acc * (scales[s] * scales[d]);
}

// ---- Fallback: direct f32 kernel (if d_ws too small) ----
__global__ void gather_dot_f32(const float* __restrict__ emb,
                               const int* __restrict__ src,
                               const int* __restrict__ dst,
                               float* __restrict__ out, int n_edges) {
    int tid  = blockIdx.x * blockDim.x + threadIdx.x;
    int lane = tid & 31;
    int edge = tid >> 5;
    if (edge >= n_edges) return;
    size_t s = (size_t)src[edge];
    size_t d = (size_t)dst[edge];
    float4 a = *(reinterpret_cast<const float4*>(emb + s * 128) + lane);
    float4 b = *(reinterpret_cast<const float4*>(emb + d * 128) + lane);
    float p = a.x * b.x + a.y * b.y + a.z * b.z + a.w * b.w;
    p += __shfl_xor(p, 1);
    p += __shfl_xor(p, 2);
    p += __shfl_xor(p, 4);
    p += __shfl_xor(p, 8);
    p += __shfl_xor(p, 16);
    if (lane == 0) out[edge] = p;
}

extern "C" void kernel_launch(void* const* d_in, const int* in_sizes, int n_in,
                              void* d_out, int out_size, void* d_ws, size_t ws_size,
                              hipStream_t stream) {
    const float* emb = (const float*)d_in[0];
    const int*   src = (const int*)d_in[1];
    const int*   dst = (const int*)d_in[2];
    float*       out = (float*)d_out;

    const int n_emb   = in_sizes[0];   // 12,800,000
    const int n_edges = in_sizes[1];   // 1,000,000
    const int n_rows  = n_emb / 128;   // 100,000

    const size_t q_bytes  = (size_t)n_rows * 128;
    const size_t sc_bytes = (size_t)n_rows * sizeof(float);

    if (ws_size >= q_bytes + sc_bytes) {
        uint4* qtab   = (uint4*)d_ws;
        float* scales = (float*)((char*)d_ws + q_bytes);

        {
            const int threads = 256;
            const int rows_per_block = threads / 8;
            const int blocks = (n_rows + rows_per_block - 1) / rows_per_block;
            quantize_rows_i8<<<blocks, threads, 0, stream>>>(emb, qtab, scales, n_rows);
        }
        {
            const int threads = 256;
            const int edges_per_block = threads / 8;
            const int blocks = (n_edges + edges_per_block - 1) / edges_per_block;
            gather_dot_i8<<<blocks, threads, 0, stream>>>(
                (const int4*)qtab, scales, src, dst, out, n_edges);
        }
    } else {
        const int threads = 256;
        const int edges_per_block = threads / 32;
        const int blocks = (n_edges + edges_per_block - 1) / edges_per_block;
        gather_dot_f32<<<blocks, threads, 0, stream>>>(emb, src, dst, out, n_edges);
    }
}